// Round 2
// baseline (997.076 us; speedup 1.0000x reference)
//
#include <hip/hip_runtime.h>
#include <cstdint>
#include <cstddef>

#define IN_DIM 768
#define OUT_DIM 128
#define N_NODES 100000
#define N_EDGES 1600000

typedef __bf16 bf16x8 __attribute__((ext_vector_type(8)));
typedef float f32x4 __attribute__((ext_vector_type(4)));

static __device__ __forceinline__ unsigned short f2bf(float f) {
  unsigned u = __builtin_bit_cast(unsigned, f);
  u += 0x7fffu + ((u >> 16) & 1u);      // round-to-nearest-even
  return (unsigned short)(u >> 16);
}
static __device__ __forceinline__ float bflo(unsigned u) {
  return __builtin_bit_cast(float, u << 16);
}
static __device__ __forceinline__ float bfhi(unsigned u) {
  return __builtin_bit_cast(float, u & 0xffff0000u);
}

// ---------------- CSR build ----------------

__global__ void deg_kernel(const int* __restrict__ src, const int* __restrict__ dst,
                           int* __restrict__ out_deg, int* __restrict__ in_deg) {
  int e = blockIdx.x * 256 + threadIdx.x;
  if (e < N_EDGES) {
    atomicAdd(&out_deg[src[e]], 1);
    atomicAdd(&in_deg[dst[e]], 1);
  }
}

// ---- 3-phase multi-block exclusive scan of in_deg -> row_start[0..N_NODES] ----
__global__ __launch_bounds__(256) void scanA_kernel(const int* __restrict__ in_deg,
                                                    int* __restrict__ row_start,
                                                    int* __restrict__ blk_sums) {
  __shared__ int sm[256];
  const int tid = threadIdx.x;
  const int base = blockIdx.x * 1024;
  int idx = base + tid * 4;
  int v0 = (idx + 0 < N_NODES) ? in_deg[idx + 0] : 0;
  int v1 = (idx + 1 < N_NODES) ? in_deg[idx + 1] : 0;
  int v2 = (idx + 2 < N_NODES) ? in_deg[idx + 2] : 0;
  int v3 = (idx + 3 < N_NODES) ? in_deg[idx + 3] : 0;
  int t0 = v0, t1 = t0 + v1, t2 = t1 + v2, t3 = t2 + v3;
  sm[tid] = t3;
  __syncthreads();
  for (int off = 1; off < 256; off <<= 1) {
    int x = (tid >= off) ? sm[tid - off] : 0;
    __syncthreads();
    sm[tid] += x;
    __syncthreads();
  }
  int base_sum = tid ? sm[tid - 1] : 0;
  if (idx + 0 < N_NODES) row_start[idx + 0] = base_sum;
  if (idx + 1 < N_NODES) row_start[idx + 1] = base_sum + t0;
  if (idx + 2 < N_NODES) row_start[idx + 2] = base_sum + t1;
  if (idx + 3 < N_NODES) row_start[idx + 3] = base_sum + t2;
  if (tid == 255) blk_sums[blockIdx.x] = sm[255];
}

__global__ void scanB_kernel(const int* __restrict__ blk_sums, int* __restrict__ blk_off) {
  __shared__ int sm[128];
  const int tid = threadIdx.x;
  const int nblk = (N_NODES + 1023) / 1024;
  int v = (tid < nblk) ? blk_sums[tid] : 0;
  sm[tid] = v;
  __syncthreads();
  for (int off = 1; off < 128; off <<= 1) {
    int x = (tid >= off) ? sm[tid - off] : 0;
    __syncthreads();
    sm[tid] += x;
    __syncthreads();
  }
  blk_off[tid] = tid ? sm[tid - 1] : 0;
}

__global__ void scanC_kernel(int* __restrict__ row_start, const int* __restrict__ blk_off,
                             int* __restrict__ cursor) {
  int i = blockIdx.x * 256 + threadIdx.x;
  if (i < N_NODES) {
    int v = row_start[i] + blk_off[i >> 10];
    row_start[i] = v;
    cursor[i] = v;
  }
  if (i == 0) row_start[N_NODES] = N_EDGES;
}

__global__ void scatter_kernel(const int* __restrict__ src, const int* __restrict__ dst,
                               int* __restrict__ cursor, int* __restrict__ edge_src) {
  int e = blockIdx.x * 256 + threadIdx.x;
  if (e < N_EDGES) {
    int p = atomicAdd(&cursor[dst[e]], 1);
    edge_src[p] = src[e];
  }
}

// ---------------- Wd pre-transpose to bf16: WdT[n][k] ----------------

__global__ void wdt_kernel(const float* __restrict__ Wd, unsigned short* __restrict__ WdT) {
  int n = blockIdx.x;          // 0..127
  int k = threadIdx.x;         // 0..767
  WdT[(size_t)n * IN_DIM + k] = f2bf(Wd[(size_t)k * OUT_DIM + n]);
}

// ---------------- GEMM1: h_bf16 = bf16((feat @ Wd + bd) * rsqrt(max(deg,1))) ----------------
// BM=64, BN=128 (full), BK=64, 4 waves each 32x64, reg-prefetch double-buffer

__global__ __launch_bounds__(256) void gemm1_kernel(
    const float* __restrict__ feat, const unsigned short* __restrict__ WdT,
    const float* __restrict__ bd, const int* __restrict__ out_deg,
    unsigned short* __restrict__ hbf) {
  __shared__ unsigned short a_lds[64][72];    // [m][k], pad 64->72
  __shared__ unsigned short b_lds[128][72];   // [n][k]
  const int tid = threadIdx.x;
  const int wave = tid >> 6;
  const int lane = tid & 63;
  const int mrow = (wave >> 1) * 32;
  const int ncol = (wave & 1) * 64;
  const int block_m = blockIdx.x * 64;
  const int fm = lane & 15;
  const int fq = lane >> 4;

  // staging index split (same coverage as before, loop-invariant parts hoisted)
  const int ar = tid >> 4;            // A row = ar + p*16
  const int ac4 = (tid & 15) * 4;     // A col (floats)
  const int bn = tid >> 3;            // B n-row = bn + p*32
  const int bch = (tid & 7) * 8;      // B col (shorts)

  f32x4 acc[2][4] = {};
  float4 av[4];
  uint4 bv[4];

  // prologue: load k0 = 0 into registers
#pragma unroll
  for (int p = 0; p < 4; ++p) {
    int gr = block_m + ar + p * 16;
    av[p] = (gr < N_NODES) ? *(const float4*)(feat + (size_t)gr * IN_DIM + ac4)
                           : make_float4(0.f, 0.f, 0.f, 0.f);
  }
#pragma unroll
  for (int p = 0; p < 4; ++p)
    bv[p] = *(const uint4*)(WdT + (size_t)(bn + p * 32) * IN_DIM + bch);

  for (int k0 = 0; k0 < IN_DIM; k0 += 64) {
    // write staged registers into LDS (convert A to bf16)
#pragma unroll
    for (int p = 0; p < 4; ++p) {
      ushort4 s;
      s.x = f2bf(av[p].x); s.y = f2bf(av[p].y); s.z = f2bf(av[p].z); s.w = f2bf(av[p].w);
      *(ushort4*)&a_lds[ar + p * 16][ac4] = s;
    }
#pragma unroll
    for (int p = 0; p < 4; ++p)
      *(uint4*)&b_lds[bn + p * 32][bch] = bv[p];
    __syncthreads();
    // issue next-tile loads BEFORE compute; MFMA hides the HBM latency
    int kn = k0 + 64;
    if (kn < IN_DIM) {
#pragma unroll
      for (int p = 0; p < 4; ++p) {
        int gr = block_m + ar + p * 16;
        av[p] = (gr < N_NODES) ? *(const float4*)(feat + (size_t)gr * IN_DIM + kn + ac4)
                               : make_float4(0.f, 0.f, 0.f, 0.f);
      }
#pragma unroll
      for (int p = 0; p < 4; ++p)
        bv[p] = *(const uint4*)(WdT + (size_t)(bn + p * 32) * IN_DIM + kn + bch);
    }
#pragma unroll
    for (int ks = 0; ks < 64; ks += 32) {
      int kc = ks + fq * 8;
      bf16x8 af[2], bfr[4];
      af[0] = *(const bf16x8*)&a_lds[mrow + fm][kc];
      af[1] = *(const bf16x8*)&a_lds[mrow + 16 + fm][kc];
#pragma unroll
      for (int i = 0; i < 4; ++i)
        bfr[i] = *(const bf16x8*)&b_lds[ncol + i * 16 + fm][kc];
#pragma unroll
      for (int mi = 0; mi < 2; ++mi)
#pragma unroll
        for (int ni = 0; ni < 4; ++ni)
          acc[mi][ni] = __builtin_amdgcn_mfma_f32_16x16x32_bf16(af[mi], bfr[ni], acc[mi][ni], 0, 0, 0);
    }
    __syncthreads();
  }
  // epilogue: (acc + bd[col]) * rsqrt(max(out_deg,1)) -> bf16
  const int fr = fq * 4;
#pragma unroll
  for (int mi = 0; mi < 2; ++mi) {
#pragma unroll
    for (int r = 0; r < 4; ++r) {
      int row = block_m + mrow + mi * 16 + fr + r;
      if (row < N_NODES) {
        float ns = rsqrtf(fmaxf((float)out_deg[row], 1.0f));
#pragma unroll
        for (int ni = 0; ni < 4; ++ni) {
          int col = ncol + ni * 16 + fm;
          float val = (acc[mi][ni][r] + bd[col]) * ns;
          hbf[(size_t)row * OUT_DIM + col] = f2bf(val);
        }
      }
    }
  }
}

// ---------------- aggregation: one wave per dst node, constant 8-wide MLP ----------------

__global__ __launch_bounds__(256) void agg_kernel(
    const unsigned short* __restrict__ hbf, const int* __restrict__ row_start,
    const int* __restrict__ edge_src, unsigned short* __restrict__ aggb) {
  const int wave = threadIdx.x >> 6;
  const int lane = threadIdx.x & 63;
  const int v = blockIdx.x * 4 + wave;
  if (v >= N_NODES) return;
  const int beg = row_start[v];
  const int end = row_start[v + 1];
  const unsigned* hp = (const unsigned*)hbf;  // 64 uints per node row (128 bf16)
  float a0 = 0.f, a1 = 0.f;
  for (int c = beg; c < end; c += 64) {
    int rem = end - c;
    int n = rem < 64 ? rem : 64;
    int sv = (c + lane < end) ? edge_src[c + lane] : 0;
    int l = n - 1;
    for (int j = 0; j < n; j += 8) {
      // masked 8-wide group: all 8 gathers always in flight (clamped index, 0/1 weight)
      int j1 = j + 1, j2 = j + 2, j3 = j + 3, j4 = j + 4, j5 = j + 5, j6 = j + 6, j7 = j + 7;
      int s0 = __shfl(sv, j);
      int s1 = __shfl(sv, j1 < n ? j1 : l);
      int s2 = __shfl(sv, j2 < n ? j2 : l);
      int s3 = __shfl(sv, j3 < n ? j3 : l);
      int s4 = __shfl(sv, j4 < n ? j4 : l);
      int s5 = __shfl(sv, j5 < n ? j5 : l);
      int s6 = __shfl(sv, j6 < n ? j6 : l);
      int s7 = __shfl(sv, j7 < n ? j7 : l);
      unsigned u0 = hp[(size_t)s0 * 64 + lane];
      unsigned u1 = hp[(size_t)s1 * 64 + lane];
      unsigned u2 = hp[(size_t)s2 * 64 + lane];
      unsigned u3 = hp[(size_t)s3 * 64 + lane];
      unsigned u4 = hp[(size_t)s4 * 64 + lane];
      unsigned u5 = hp[(size_t)s5 * 64 + lane];
      unsigned u6 = hp[(size_t)s6 * 64 + lane];
      unsigned u7 = hp[(size_t)s7 * 64 + lane];
      float w1 = j1 < n ? 1.f : 0.f;
      float w2 = j2 < n ? 1.f : 0.f;
      float w3 = j3 < n ? 1.f : 0.f;
      float w4 = j4 < n ? 1.f : 0.f;
      float w5 = j5 < n ? 1.f : 0.f;
      float w6 = j6 < n ? 1.f : 0.f;
      float w7 = j7 < n ? 1.f : 0.f;
      a0 += bflo(u0);            a1 += bfhi(u0);
      a0 = fmaf(w1, bflo(u1), a0); a1 = fmaf(w1, bfhi(u1), a1);
      a0 = fmaf(w2, bflo(u2), a0); a1 = fmaf(w2, bfhi(u2), a1);
      a0 = fmaf(w3, bflo(u3), a0); a1 = fmaf(w3, bfhi(u3), a1);
      a0 = fmaf(w4, bflo(u4), a0); a1 = fmaf(w4, bfhi(u4), a1);
      a0 = fmaf(w5, bflo(u5), a0); a1 = fmaf(w5, bfhi(u5), a1);
      a0 = fmaf(w6, bflo(u6), a0); a1 = fmaf(w6, bfhi(u6), a1);
      a0 = fmaf(w7, bflo(u7), a0); a1 = fmaf(w7, bfhi(u7), a1);
    }
  }
  float nd = rsqrtf(fmaxf((float)(end - beg), 1.0f));
  a0 *= nd; a1 *= nd;
  unsigned o = (unsigned)f2bf(a0) | ((unsigned)f2bf(a1) << 16);
  ((unsigned*)aggb)[(size_t)v * 64 + lane] = o;
}

// ---------------- fold Wg@Wu and bg@Wu+bu ----------------

__global__ void wgu_kernel(const float* __restrict__ Wg, const float* __restrict__ Wu,
                           unsigned short* __restrict__ WguT) {
  int i = blockIdx.x * 256 + threadIdx.x;     // over 128*768
  if (i >= 128 * 768) return;
  int r = i / 768, c = i % 768;
  float s = 0.f;
  for (int k = 0; k < 128; ++k) s += Wg[r * 128 + k] * Wu[(size_t)k * 768 + c];
  WguT[(size_t)c * 128 + r] = f2bf(s);        // stored transposed: [n=768][k=128]
}

__global__ void bgu_kernel(const float* __restrict__ bg, const float* __restrict__ Wu,
                           const float* __restrict__ bu, float* __restrict__ bgu) {
  int c = blockIdx.x * 256 + threadIdx.x;
  if (c >= 768) return;
  float s = bu[c];
  for (int k = 0; k < 128; ++k) s += bg[k] * Wu[(size_t)k * 768 + c];
  bgu[c] = s;
}

// ---------------- GEMM3: out = agg_bf16 @ Wgu + bgu (fp32 out) ----------------
// BM=128, BN=128, K=128; flat grid n-fastest + bijective XCD chunk swizzle; reg prefetch

__global__ __launch_bounds__(256) void gemm3_kernel(
    const unsigned short* __restrict__ aggb, const unsigned short* __restrict__ WguT,
    const float* __restrict__ bgu, float* __restrict__ out) {
  __shared__ unsigned short a_lds[128][72];   // [m][k], pad 64->72
  __shared__ unsigned short b_lds[128][72];   // [n][k]
  const int tid = threadIdx.x;
  const int wave = tid >> 6;
  const int lane = tid & 63;
  const int m_off = (wave >> 1) * 64;
  const int n_off = (wave & 1) * 64;
  // bijective XCD swizzle (m204): nwg = 782*6 = 4692, not divisible by 8
  const int nwg = ((N_NODES + 127) / 128) * 6;
  int orig = blockIdx.x;
  int q = nwg >> 3, r8 = nwg & 7;
  int xcd = orig & 7, off = orig >> 3;
  int wgid = (xcd < r8 ? xcd * (q + 1) : r8 * (q + 1) + (xcd - r8) * q) + off;
  const int block_m = (wgid / 6) * 128;
  const int block_n = (wgid % 6) * 128;
  const int fm = lane & 15;
  const int fq = lane >> 4;

  const int sr = tid >> 3;           // row = sr + p*32
  const int sch = (tid & 7) * 8;     // col (shorts)

  f32x4 acc[4][4] = {};
  uint4 avv[4], bvv[4];

  // prologue: k0 = 0
#pragma unroll
  for (int p = 0; p < 4; ++p) {
    int rr = sr + p * 32;
    int gr = block_m + rr;
    avv[p] = (gr < N_NODES) ? *(const uint4*)(aggb + (size_t)gr * 128 + sch)
                            : make_uint4(0u, 0u, 0u, 0u);
    bvv[p] = *(const uint4*)(WguT + (size_t)(block_n + rr) * 128 + sch);
  }

  for (int k0 = 0; k0 < 128; k0 += 64) {
#pragma unroll
    for (int p = 0; p < 4; ++p) {
      int rr = sr + p * 32;
      *(uint4*)&a_lds[rr][sch] = avv[p];
      *(uint4*)&b_lds[rr][sch] = bvv[p];
    }
    __syncthreads();
    if (k0 == 0) {
#pragma unroll
      for (int p = 0; p < 4; ++p) {
        int rr = sr + p * 32;
        int gr = block_m + rr;
        avv[p] = (gr < N_NODES) ? *(const uint4*)(aggb + (size_t)gr * 128 + 64 + sch)
                                : make_uint4(0u, 0u, 0u, 0u);
        bvv[p] = *(const uint4*)(WguT + (size_t)(block_n + rr) * 128 + 64 + sch);
      }
    }
#pragma unroll
    for (int ks = 0; ks < 64; ks += 32) {
      bf16x8 af[4], bfr[4];
      int kc = ks + fq * 8;
#pragma unroll
      for (int i = 0; i < 4; ++i) af[i] = *(const bf16x8*)&a_lds[m_off + i * 16 + fm][kc];
#pragma unroll
      for (int i = 0; i < 4; ++i) bfr[i] = *(const bf16x8*)&b_lds[n_off + i * 16 + fm][kc];
#pragma unroll
      for (int mi = 0; mi < 4; ++mi)
#pragma unroll
        for (int ni = 0; ni < 4; ++ni)
          acc[mi][ni] = __builtin_amdgcn_mfma_f32_16x16x32_bf16(af[mi], bfr[ni], acc[mi][ni], 0, 0, 0);
    }
    __syncthreads();
  }
  const int fr = fq * 4;
#pragma unroll
  for (int mi = 0; mi < 4; ++mi) {
#pragma unroll
    for (int r = 0; r < 4; ++r) {
      int row = block_m + m_off + mi * 16 + fr + r;
      if (row < N_NODES) {
#pragma unroll
        for (int ni = 0; ni < 4; ++ni) {
          int col = block_n + n_off + ni * 16 + fm;
          out[(size_t)row * IN_DIM + col] = acc[mi][ni][r] + bgu[col];
        }
      }
    }
  }
}

// ---------------- launch ----------------

extern "C" void kernel_launch(void* const* d_in, const int* in_sizes, int n_in,
                              void* d_out, int out_size, void* d_ws, size_t ws_size,
                              hipStream_t stream) {
  (void)in_sizes; (void)n_in; (void)out_size; (void)ws_size;
  const float* feat = (const float*)d_in[0];
  const float* Wd   = (const float*)d_in[1];
  const float* bd   = (const float*)d_in[2];
  const float* Wg   = (const float*)d_in[3];
  const float* bg   = (const float*)d_in[4];
  const float* Wu   = (const float*)d_in[5];
  const float* bu   = (const float*)d_in[6];
  const int*   src  = (const int*)d_in[7];
  const int*   dst  = (const int*)d_in[8];
  float* out = (float*)d_out;

  char* ws = (char*)d_ws;
  unsigned short* hbf       = (unsigned short*)(ws + 0);          // 25,600,000
  unsigned short* aggb      = (unsigned short*)(ws + 25600000);   // 25,600,000
  int*            edge_srcs = (int*)(ws + 51200000);              //  6,400,000
  int*            out_deg   = (int*)(ws + 57600000);              //    400,000
  int*            in_deg    = (int*)(ws + 58000000);              //    400,000
  int*            row_start = (int*)(ws + 58400000);              //    400,004
  int*            cursor    = (int*)(ws + 58800128);              //    400,000
  unsigned short* WguT      = (unsigned short*)(ws + 59600128);   //    196,608
  float*          bgu       = (float*)(ws + 59796736);            //      3,072
  unsigned short* WdT       = (unsigned short*)(ws + 59799808);   //    196,608
  int*            blk_sums  = (int*)(ws + 59996416);              //        512
  int*            blk_off   = (int*)(ws + 59996928);              //        512

  // zero both degree arrays (contiguous 800,000 B)
  hipMemsetAsync(out_deg, 0, 800000, stream);
  deg_kernel<<<(N_EDGES + 255) / 256, 256, 0, stream>>>(src, dst, out_deg, in_deg);
  scanA_kernel<<<(N_NODES + 1023) / 1024, 256, 0, stream>>>(in_deg, row_start, blk_sums);
  scanB_kernel<<<1, 128, 0, stream>>>(blk_sums, blk_off);
  scanC_kernel<<<(N_NODES + 255) / 256, 256, 0, stream>>>(row_start, blk_off, cursor);
  scatter_kernel<<<(N_EDGES + 255) / 256, 256, 0, stream>>>(src, dst, cursor, edge_srcs);
  wdt_kernel<<<128, 768, 0, stream>>>(Wd, WdT);
  gemm1_kernel<<<(N_NODES + 63) / 64, 256, 0, stream>>>(feat, WdT, bd, out_deg, hbf);
  agg_kernel<<<(N_NODES + 3) / 4, 256, 0, stream>>>(hbf, row_start, edge_srcs, aggb);
  wgu_kernel<<<(128 * 768 + 255) / 256, 256, 0, stream>>>(Wg, Wu, WguT);
  bgu_kernel<<<3, 256, 0, stream>>>(bg, Wu, bu, bgu);
  gemm3_kernel<<<((N_NODES + 127) / 128) * 6, 256, 0, stream>>>(aggb, WguT, bgu, out);
}

// Round 4
// 940.159 us; speedup vs baseline: 1.0605x; 1.0605x over previous
//
#include <hip/hip_runtime.h>
#include <cstdint>
#include <cstddef>

#define IN_DIM 768
#define OUT_DIM 128
#define N_NODES 100000
#define N_EDGES 1600000

typedef __bf16 bf16x8 __attribute__((ext_vector_type(8)));
typedef float f32x4 __attribute__((ext_vector_type(4)));

static __device__ __forceinline__ unsigned short f2bf(float f) {
  unsigned u = __builtin_bit_cast(unsigned, f);
  u += 0x7fffu + ((u >> 16) & 1u);      // round-to-nearest-even
  return (unsigned short)(u >> 16);
}
static __device__ __forceinline__ float bflo(unsigned u) {
  return __builtin_bit_cast(float, u << 16);
}
static __device__ __forceinline__ float bfhi(unsigned u) {
  return __builtin_bit_cast(float, u & 0xffff0000u);
}

// ---------------- CSR build ----------------

__global__ void deg_kernel(const int* __restrict__ src, const int* __restrict__ dst,
                           int* __restrict__ out_deg, int* __restrict__ in_deg) {
  int e = blockIdx.x * 256 + threadIdx.x;
  if (e < N_EDGES) {
    atomicAdd(&out_deg[src[e]], 1);
    atomicAdd(&in_deg[dst[e]], 1);
  }
}

// ---- 3-phase multi-block exclusive scan of in_deg -> row_start[0..N_NODES] ----
__global__ __launch_bounds__(256) void scanA_kernel(const int* __restrict__ in_deg,
                                                    int* __restrict__ row_start,
                                                    int* __restrict__ blk_sums) {
  __shared__ int sm[256];
  const int tid = threadIdx.x;
  const int base = blockIdx.x * 1024;
  int idx = base + tid * 4;
  int v0 = (idx + 0 < N_NODES) ? in_deg[idx + 0] : 0;
  int v1 = (idx + 1 < N_NODES) ? in_deg[idx + 1] : 0;
  int v2 = (idx + 2 < N_NODES) ? in_deg[idx + 2] : 0;
  int v3 = (idx + 3 < N_NODES) ? in_deg[idx + 3] : 0;
  int t0 = v0, t1 = t0 + v1, t2 = t1 + v2, t3 = t2 + v3;
  sm[tid] = t3;
  __syncthreads();
  for (int off = 1; off < 256; off <<= 1) {
    int x = (tid >= off) ? sm[tid - off] : 0;
    __syncthreads();
    sm[tid] += x;
    __syncthreads();
  }
  int base_sum = tid ? sm[tid - 1] : 0;
  if (idx + 0 < N_NODES) row_start[idx + 0] = base_sum;
  if (idx + 1 < N_NODES) row_start[idx + 1] = base_sum + t0;
  if (idx + 2 < N_NODES) row_start[idx + 2] = base_sum + t1;
  if (idx + 3 < N_NODES) row_start[idx + 3] = base_sum + t2;
  if (tid == 255) blk_sums[blockIdx.x] = sm[255];
}

__global__ void scanB_kernel(const int* __restrict__ blk_sums, int* __restrict__ blk_off) {
  __shared__ int sm[128];
  const int tid = threadIdx.x;
  const int nblk = (N_NODES + 1023) / 1024;
  int v = (tid < nblk) ? blk_sums[tid] : 0;
  sm[tid] = v;
  __syncthreads();
  for (int off = 1; off < 128; off <<= 1) {
    int x = (tid >= off) ? sm[tid - off] : 0;
    __syncthreads();
    sm[tid] += x;
    __syncthreads();
  }
  blk_off[tid] = tid ? sm[tid - 1] : 0;
}

__global__ void scanC_kernel(int* __restrict__ row_start, const int* __restrict__ blk_off,
                             int* __restrict__ cursor) {
  int i = blockIdx.x * 256 + threadIdx.x;
  if (i < N_NODES) {
    int v = row_start[i] + blk_off[i >> 10];
    row_start[i] = v;
    cursor[i] = v;
  }
  if (i == 0) row_start[N_NODES] = N_EDGES;
}

__global__ void scatter_kernel(const int* __restrict__ src, const int* __restrict__ dst,
                               int* __restrict__ cursor, int* __restrict__ edge_src) {
  int e = blockIdx.x * 256 + threadIdx.x;
  if (e < N_EDGES) {
    int p = atomicAdd(&cursor[dst[e]], 1);
    edge_src[p] = src[e];
  }
}

// ---------------- Wd pre-transpose to bf16: WdT[n][k] ----------------

__global__ void wdt_kernel(const float* __restrict__ Wd, unsigned short* __restrict__ WdT) {
  int n = blockIdx.x;          // 0..127
  int k = threadIdx.x;         // 0..767
  WdT[(size_t)n * IN_DIM + k] = f2bf(Wd[(size_t)k * OUT_DIM + n]);
}

// ---------------- GEMM1: h_bf16 = bf16((feat @ Wd + bd) * rsqrt(max(deg,1))) ----------------
// BM=64, BN=128 (full), BK=64, 4 waves each 32x64  (round-1 measured structure)

__global__ __launch_bounds__(256) void gemm1_kernel(
    const float* __restrict__ feat, const unsigned short* __restrict__ WdT,
    const float* __restrict__ bd, const int* __restrict__ out_deg,
    unsigned short* __restrict__ hbf) {
  __shared__ unsigned short a_lds[64][72];    // [m][k], pad 64->72
  __shared__ unsigned short b_lds[128][72];   // [n][k]
  const int tid = threadIdx.x;
  const int wave = tid >> 6;
  const int lane = tid & 63;
  const int mrow = (wave >> 1) * 32;
  const int ncol = (wave & 1) * 64;
  const int block_m = blockIdx.x * 64;
  const int fm = lane & 15;
  const int fq = lane >> 4;

  f32x4 acc[2][4] = {};

  for (int k0 = 0; k0 < IN_DIM; k0 += 64) {
    // stage A: 64 rows x 64 k fp32 -> bf16  (1024 float4 chunks)
#pragma unroll
    for (int p = 0; p < 4; ++p) {
      int idx = tid + p * 256;
      int r = idx >> 4;
      int c4 = (idx & 15) * 4;
      int gr = block_m + r;
      float4 v;
      if (gr < N_NODES) v = *(const float4*)(feat + (size_t)gr * IN_DIM + k0 + c4);
      else v = make_float4(0.f, 0.f, 0.f, 0.f);
      ushort4 s;
      s.x = f2bf(v.x); s.y = f2bf(v.y); s.z = f2bf(v.z); s.w = f2bf(v.w);
      *(ushort4*)&a_lds[r][c4] = s;
    }
    // stage B: 128 n-rows x 64 k bf16 from WdT  (1024 uint4 chunks)
#pragma unroll
    for (int p = 0; p < 4; ++p) {
      int idx = tid + p * 256;
      int n = idx >> 3;
      int ch = (idx & 7) * 8;
      uint4 v = *(const uint4*)(WdT + (size_t)n * IN_DIM + k0 + ch);
      *(uint4*)&b_lds[n][ch] = v;
    }
    __syncthreads();
#pragma unroll
    for (int ks = 0; ks < 64; ks += 32) {
      int kc = ks + fq * 8;
      bf16x8 af[2], bfr[4];
      af[0] = *(const bf16x8*)&a_lds[mrow + fm][kc];
      af[1] = *(const bf16x8*)&a_lds[mrow + 16 + fm][kc];
#pragma unroll
      for (int i = 0; i < 4; ++i)
        bfr[i] = *(const bf16x8*)&b_lds[ncol + i * 16 + fm][kc];
#pragma unroll
      for (int mi = 0; mi < 2; ++mi)
#pragma unroll
        for (int ni = 0; ni < 4; ++ni)
          acc[mi][ni] = __builtin_amdgcn_mfma_f32_16x16x32_bf16(af[mi], bfr[ni], acc[mi][ni], 0, 0, 0);
    }
    __syncthreads();
  }
  // epilogue: (acc + bd[col]) * rsqrt(max(out_deg,1)) -> bf16
  const int fr = fq * 4;
#pragma unroll
  for (int mi = 0; mi < 2; ++mi) {
#pragma unroll
    for (int r = 0; r < 4; ++r) {
      int row = block_m + mrow + mi * 16 + fr + r;
      if (row < N_NODES) {
        float ns = rsqrtf(fmaxf((float)out_deg[row], 1.0f));
#pragma unroll
        for (int ni = 0; ni < 4; ++ni) {
          int col = ncol + ni * 16 + fm;
          float val = (acc[mi][ni][r] + bd[col]) * ns;
          hbf[(size_t)row * OUT_DIM + col] = f2bf(val);
        }
      }
    }
  }
}

// ---------------- aggregation: one wave per dst node (round-1 measured structure) ----------------

__global__ __launch_bounds__(256) void agg_kernel(
    const unsigned short* __restrict__ hbf, const int* __restrict__ row_start,
    const int* __restrict__ edge_src, unsigned short* __restrict__ aggb) {
  const int wave = threadIdx.x >> 6;
  const int lane = threadIdx.x & 63;
  const int v = blockIdx.x * 4 + wave;
  if (v >= N_NODES) return;
  const int beg = row_start[v];
  const int end = row_start[v + 1];
  const unsigned* hp = (const unsigned*)hbf;  // 64 uints per node row (128 bf16)
  float a0 = 0.f, a1 = 0.f;
  for (int c = beg; c < end; c += 64) {
    int rem = end - c;
    int n = rem < 64 ? rem : 64;
    int sv = (c + lane < end) ? edge_src[c + lane] : 0;
    int j = 0;
    for (; j + 4 <= n; j += 4) {
      int s0 = __shfl(sv, j + 0);
      int s1 = __shfl(sv, j + 1);
      int s2 = __shfl(sv, j + 2);
      int s3 = __shfl(sv, j + 3);
      unsigned u0 = hp[(size_t)s0 * 64 + lane];
      unsigned u1 = hp[(size_t)s1 * 64 + lane];
      unsigned u2 = hp[(size_t)s2 * 64 + lane];
      unsigned u3 = hp[(size_t)s3 * 64 + lane];
      a0 += (bflo(u0) + bflo(u1)) + (bflo(u2) + bflo(u3));
      a1 += (bfhi(u0) + bfhi(u1)) + (bfhi(u2) + bfhi(u3));
    }
    for (; j < n; ++j) {
      int s = __shfl(sv, j);
      unsigned u = hp[(size_t)s * 64 + lane];
      a0 += bflo(u);
      a1 += bfhi(u);
    }
  }
  float nd = rsqrtf(fmaxf((float)(end - beg), 1.0f));
  a0 *= nd; a1 *= nd;
  unsigned o = (unsigned)f2bf(a0) | ((unsigned)f2bf(a1) << 16);
  ((unsigned*)aggb)[(size_t)v * 64 + lane] = o;
}

// ---------------- fold Wg@Wu and bg@Wu+bu ----------------

__global__ void wgu_kernel(const float* __restrict__ Wg, const float* __restrict__ Wu,
                           unsigned short* __restrict__ WguT) {
  int i = blockIdx.x * 256 + threadIdx.x;     // over 128*768
  if (i >= 128 * 768) return;
  int r = i / 768, c = i % 768;
  float s = 0.f;
  for (int k = 0; k < 128; ++k) s += Wg[r * 128 + k] * Wu[(size_t)k * 768 + c];
  WguT[(size_t)c * 128 + r] = f2bf(s);        // stored transposed: [n=768][k=128]
}

__global__ void bgu_kernel(const float* __restrict__ bg, const float* __restrict__ Wu,
                           const float* __restrict__ bu, float* __restrict__ bgu) {
  int c = blockIdx.x * 256 + threadIdx.x;
  if (c >= 768) return;
  float s = bu[c];
  for (int k = 0; k < 128; ++k) s += bg[k] * Wu[(size_t)k * 768 + c];
  bgu[c] = s;
}

// ---------------- GEMM3: out = agg_bf16 @ Wgu + bgu (fp32 out) ----------------
// BM=128, BN=128, K=128. Both K-halves loaded to registers upfront (single
// HBM-latency exposure), two LDS compute phases. Grid dim3(6, 782): n fastest
// so the 6 blocks sharing an A-tile dispatch consecutively (L2/L3 locality).

__global__ __launch_bounds__(256) void gemm3_kernel(
    const unsigned short* __restrict__ aggb, const unsigned short* __restrict__ WguT,
    const float* __restrict__ bgu, float* __restrict__ out) {
  __shared__ unsigned short a_lds[128][72];   // [m][k-half], pad 64->72
  __shared__ unsigned short b_lds[128][72];   // [n][k-half]
  const int tid = threadIdx.x;
  const int wave = tid >> 6;
  const int lane = tid & 63;
  const int m_off = (wave >> 1) * 64;
  const int n_off = (wave & 1) * 64;
  const int block_n = blockIdx.x * 128;   // 0..5
  const int block_m = blockIdx.y * 128;   // 0..781
  const int fm = lane & 15;
  const int fq = lane >> 4;

  const int sr = tid >> 3;           // row = sr + p*32
  const int sch = (tid & 7) * 8;     // col (shorts)

  // load BOTH K-halves into registers upfront: all 16 loads in flight at once
  uint4 av0[4], bv0[4], av1[4], bv1[4];
#pragma unroll
  for (int p = 0; p < 4; ++p) {
    int rr = sr + p * 32;
    int gr = block_m + rr;
    const unsigned short* ap = aggb + (size_t)gr * 128 + sch;
    const unsigned short* bp = WguT + (size_t)(block_n + rr) * 128 + sch;
    bool ok = gr < N_NODES;
    av0[p] = ok ? *(const uint4*)(ap)      : make_uint4(0u, 0u, 0u, 0u);
    av1[p] = ok ? *(const uint4*)(ap + 64) : make_uint4(0u, 0u, 0u, 0u);
    bv0[p] = *(const uint4*)(bp);
    bv1[p] = *(const uint4*)(bp + 64);
  }

  f32x4 acc[4][4] = {};

  // ---- phase 0: k = 0..63 ----
#pragma unroll
  for (int p = 0; p < 4; ++p) {
    int rr = sr + p * 32;
    *(uint4*)&a_lds[rr][sch] = av0[p];
    *(uint4*)&b_lds[rr][sch] = bv0[p];
  }
  __syncthreads();
#pragma unroll
  for (int ks = 0; ks < 64; ks += 32) {
    bf16x8 af[4], bfr[4];
    int kc = ks + fq * 8;
#pragma unroll
    for (int i = 0; i < 4; ++i) af[i] = *(const bf16x8*)&a_lds[m_off + i * 16 + fm][kc];
#pragma unroll
    for (int i = 0; i < 4; ++i) bfr[i] = *(const bf16x8*)&b_lds[n_off + i * 16 + fm][kc];
#pragma unroll
    for (int mi = 0; mi < 4; ++mi)
#pragma unroll
      for (int ni = 0; ni < 4; ++ni)
        acc[mi][ni] = __builtin_amdgcn_mfma_f32_16x16x32_bf16(af[mi], bfr[ni], acc[mi][ni], 0, 0, 0);
  }
  __syncthreads();
  // ---- phase 1: k = 64..127 ----
#pragma unroll
  for (int p = 0; p < 4; ++p) {
    int rr = sr + p * 32;
    *(uint4*)&a_lds[rr][sch] = av1[p];
    *(uint4*)&b_lds[rr][sch] = bv1[p];
  }
  __syncthreads();
#pragma unroll
  for (int ks = 0; ks < 64; ks += 32) {
    bf16x8 af[4], bfr[4];
    int kc = ks + fq * 8;
#pragma unroll
    for (int i = 0; i < 4; ++i) af[i] = *(const bf16x8*)&a_lds[m_off + i * 16 + fm][kc];
#pragma unroll
    for (int i = 0; i < 4; ++i) bfr[i] = *(const bf16x8*)&b_lds[n_off + i * 16 + fm][kc];
#pragma unroll
    for (int mi = 0; mi < 4; ++mi)
#pragma unroll
      for (int ni = 0; ni < 4; ++ni)
        acc[mi][ni] = __builtin_amdgcn_mfma_f32_16x16x32_bf16(af[mi], bfr[ni], acc[mi][ni], 0, 0, 0);
  }

  const int fr = fq * 4;
#pragma unroll
  for (int mi = 0; mi < 4; ++mi) {
#pragma unroll
    for (int r = 0; r < 4; ++r) {
      int row = block_m + m_off + mi * 16 + fr + r;
      if (row < N_NODES) {
#pragma unroll
        for (int ni = 0; ni < 4; ++ni) {
          int col = block_n + n_off + ni * 16 + fm;
          out[(size_t)row * IN_DIM + col] = acc[mi][ni][r] + bgu[col];
        }
      }
    }
  }
}

// ---------------- launch ----------------

extern "C" void kernel_launch(void* const* d_in, const int* in_sizes, int n_in,
                              void* d_out, int out_size, void* d_ws, size_t ws_size,
                              hipStream_t stream) {
  (void)in_sizes; (void)n_in; (void)out_size; (void)ws_size;
  const float* feat = (const float*)d_in[0];
  const float* Wd   = (const float*)d_in[1];
  const float* bd   = (const float*)d_in[2];
  const float* Wg   = (const float*)d_in[3];
  const float* bg   = (const float*)d_in[4];
  const float* Wu   = (const float*)d_in[5];
  const float* bu   = (const float*)d_in[6];
  const int*   src  = (const int*)d_in[7];
  const int*   dst  = (const int*)d_in[8];
  float* out = (float*)d_out;

  char* ws = (char*)d_ws;
  unsigned short* hbf       = (unsigned short*)(ws + 0);          // 25,600,000
  unsigned short* aggb      = (unsigned short*)(ws + 25600000);   // 25,600,000
  int*            edge_srcs = (int*)(ws + 51200000);              //  6,400,000
  int*            out_deg   = (int*)(ws + 57600000);              //    400,000
  int*            in_deg    = (int*)(ws + 58000000);              //    400,000
  int*            row_start = (int*)(ws + 58400000);              //    400,004
  int*            cursor    = (int*)(ws + 58800128);              //    400,000
  unsigned short* WguT      = (unsigned short*)(ws + 59600128);   //    196,608
  float*          bgu       = (float*)(ws + 59796736);            //      3,072
  unsigned short* WdT       = (unsigned short*)(ws + 59799808);   //    196,608
  int*            blk_sums  = (int*)(ws + 59996416);              //        512
  int*            blk_off   = (int*)(ws + 59996928);              //        512

  // zero both degree arrays (contiguous 800,000 B)
  hipMemsetAsync(out_deg, 0, 800000, stream);
  deg_kernel<<<(N_EDGES + 255) / 256, 256, 0, stream>>>(src, dst, out_deg, in_deg);
  scanA_kernel<<<(N_NODES + 1023) / 1024, 256, 0, stream>>>(in_deg, row_start, blk_sums);
  scanB_kernel<<<1, 128, 0, stream>>>(blk_sums, blk_off);
  scanC_kernel<<<(N_NODES + 255) / 256, 256, 0, stream>>>(row_start, blk_off, cursor);
  scatter_kernel<<<(N_EDGES + 255) / 256, 256, 0, stream>>>(src, dst, cursor, edge_srcs);
  wdt_kernel<<<128, 768, 0, stream>>>(Wd, WdT);
  gemm1_kernel<<<(N_NODES + 63) / 64, 256, 0, stream>>>(feat, WdT, bd, out_deg, hbf);
  agg_kernel<<<(N_NODES + 3) / 4, 256, 0, stream>>>(hbf, row_start, edge_srcs, aggb);
  wgu_kernel<<<(128 * 768 + 255) / 256, 256, 0, stream>>>(Wg, Wu, WguT);
  bgu_kernel<<<3, 256, 0, stream>>>(bg, Wu, bu, bgu);
  gemm3_kernel<<<dim3(6, (N_NODES + 127) / 128), 256, 0, stream>>>(aggb, WguT, bgu, out);
}

// Round 5
// 934.630 us; speedup vs baseline: 1.0668x; 1.0059x over previous
//
#include <hip/hip_runtime.h>
#include <cstdint>
#include <cstddef>

#define IN_DIM 768
#define OUT_DIM 128
#define N_NODES 100000
#define N_EDGES 1600000

typedef __bf16 bf16x8 __attribute__((ext_vector_type(8)));
typedef float f32x4 __attribute__((ext_vector_type(4)));

static __device__ __forceinline__ unsigned short f2bf(float f) {
  unsigned u = __builtin_bit_cast(unsigned, f);
  u += 0x7fffu + ((u >> 16) & 1u);      // round-to-nearest-even
  return (unsigned short)(u >> 16);
}
static __device__ __forceinline__ float bflo(unsigned u) {
  return __builtin_bit_cast(float, u << 16);
}
static __device__ __forceinline__ float bfhi(unsigned u) {
  return __builtin_bit_cast(float, u & 0xffff0000u);
}

// ---------------- CSR build ----------------

__global__ void deg_kernel(const int* __restrict__ src, const int* __restrict__ dst,
                           int* __restrict__ out_deg, int* __restrict__ in_deg) {
  int e = blockIdx.x * 256 + threadIdx.x;
  if (e < N_EDGES) {
    atomicAdd(&out_deg[src[e]], 1);
    atomicAdd(&in_deg[dst[e]], 1);
  }
}

// ---- 3-phase multi-block exclusive scan of in_deg -> row_start[0..N_NODES] ----
__global__ __launch_bounds__(256) void scanA_kernel(const int* __restrict__ in_deg,
                                                    int* __restrict__ row_start,
                                                    int* __restrict__ blk_sums) {
  __shared__ int sm[256];
  const int tid = threadIdx.x;
  const int base = blockIdx.x * 1024;
  int idx = base + tid * 4;
  int v0 = (idx + 0 < N_NODES) ? in_deg[idx + 0] : 0;
  int v1 = (idx + 1 < N_NODES) ? in_deg[idx + 1] : 0;
  int v2 = (idx + 2 < N_NODES) ? in_deg[idx + 2] : 0;
  int v3 = (idx + 3 < N_NODES) ? in_deg[idx + 3] : 0;
  int t0 = v0, t1 = t0 + v1, t2 = t1 + v2, t3 = t2 + v3;
  sm[tid] = t3;
  __syncthreads();
  for (int off = 1; off < 256; off <<= 1) {
    int x = (tid >= off) ? sm[tid - off] : 0;
    __syncthreads();
    sm[tid] += x;
    __syncthreads();
  }
  int base_sum = tid ? sm[tid - 1] : 0;
  if (idx + 0 < N_NODES) row_start[idx + 0] = base_sum;
  if (idx + 1 < N_NODES) row_start[idx + 1] = base_sum + t0;
  if (idx + 2 < N_NODES) row_start[idx + 2] = base_sum + t1;
  if (idx + 3 < N_NODES) row_start[idx + 3] = base_sum + t2;
  if (tid == 255) blk_sums[blockIdx.x] = sm[255];
}

__global__ void scanB_kernel(const int* __restrict__ blk_sums, int* __restrict__ blk_off) {
  __shared__ int sm[128];
  const int tid = threadIdx.x;
  const int nblk = (N_NODES + 1023) / 1024;
  int v = (tid < nblk) ? blk_sums[tid] : 0;
  sm[tid] = v;
  __syncthreads();
  for (int off = 1; off < 128; off <<= 1) {
    int x = (tid >= off) ? sm[tid - off] : 0;
    __syncthreads();
    sm[tid] += x;
    __syncthreads();
  }
  blk_off[tid] = tid ? sm[tid - 1] : 0;
}

__global__ void scanC_kernel(int* __restrict__ row_start, const int* __restrict__ blk_off,
                             int* __restrict__ cursor) {
  int i = blockIdx.x * 256 + threadIdx.x;
  if (i < N_NODES) {
    int v = row_start[i] + blk_off[i >> 10];
    row_start[i] = v;
    cursor[i] = v;
  }
  if (i == 0) row_start[N_NODES] = N_EDGES;
}

__global__ void scatter_kernel(const int* __restrict__ src, const int* __restrict__ dst,
                               int* __restrict__ cursor, int* __restrict__ edge_src) {
  int e = blockIdx.x * 256 + threadIdx.x;
  if (e < N_EDGES) {
    int p = atomicAdd(&cursor[dst[e]], 1);
    edge_src[p] = src[e];
  }
}

// ---------------- Wd pre-transpose to bf16: WdT[n][k] ----------------

__global__ void wdt_kernel(const float* __restrict__ Wd, unsigned short* __restrict__ WdT) {
  int n = blockIdx.x;          // 0..127
  int k = threadIdx.x;         // 0..767
  WdT[(size_t)n * IN_DIM + k] = f2bf(Wd[(size_t)k * OUT_DIM + n]);
}

// ---------------- GEMM1: h_bf16 = bf16((feat @ Wd + bd) * rsqrt(max(deg,1))) ----------------
// BM=64, BN=128 (full), BK=64, 4 waves each 32x64  (round-1 measured structure)

__global__ __launch_bounds__(256) void gemm1_kernel(
    const float* __restrict__ feat, const unsigned short* __restrict__ WdT,
    const float* __restrict__ bd, const int* __restrict__ out_deg,
    unsigned short* __restrict__ hbf) {
  __shared__ unsigned short a_lds[64][72];    // [m][k], pad 64->72
  __shared__ unsigned short b_lds[128][72];   // [n][k]
  const int tid = threadIdx.x;
  const int wave = tid >> 6;
  const int lane = tid & 63;
  const int mrow = (wave >> 1) * 32;
  const int ncol = (wave & 1) * 64;
  const int block_m = blockIdx.x * 64;
  const int fm = lane & 15;
  const int fq = lane >> 4;

  f32x4 acc[2][4] = {};

  for (int k0 = 0; k0 < IN_DIM; k0 += 64) {
    // stage A: 64 rows x 64 k fp32 -> bf16  (1024 float4 chunks)
#pragma unroll
    for (int p = 0; p < 4; ++p) {
      int idx = tid + p * 256;
      int r = idx >> 4;
      int c4 = (idx & 15) * 4;
      int gr = block_m + r;
      float4 v;
      if (gr < N_NODES) v = *(const float4*)(feat + (size_t)gr * IN_DIM + k0 + c4);
      else v = make_float4(0.f, 0.f, 0.f, 0.f);
      ushort4 s;
      s.x = f2bf(v.x); s.y = f2bf(v.y); s.z = f2bf(v.z); s.w = f2bf(v.w);
      *(ushort4*)&a_lds[r][c4] = s;
    }
    // stage B: 128 n-rows x 64 k bf16 from WdT  (1024 uint4 chunks)
#pragma unroll
    for (int p = 0; p < 4; ++p) {
      int idx = tid + p * 256;
      int n = idx >> 3;
      int ch = (idx & 7) * 8;
      uint4 v = *(const uint4*)(WdT + (size_t)n * IN_DIM + k0 + ch);
      *(uint4*)&b_lds[n][ch] = v;
    }
    __syncthreads();
#pragma unroll
    for (int ks = 0; ks < 64; ks += 32) {
      int kc = ks + fq * 8;
      bf16x8 af[2], bfr[4];
      af[0] = *(const bf16x8*)&a_lds[mrow + fm][kc];
      af[1] = *(const bf16x8*)&a_lds[mrow + 16 + fm][kc];
#pragma unroll
      for (int i = 0; i < 4; ++i)
        bfr[i] = *(const bf16x8*)&b_lds[ncol + i * 16 + fm][kc];
#pragma unroll
      for (int mi = 0; mi < 2; ++mi)
#pragma unroll
        for (int ni = 0; ni < 4; ++ni)
          acc[mi][ni] = __builtin_amdgcn_mfma_f32_16x16x32_bf16(af[mi], bfr[ni], acc[mi][ni], 0, 0, 0);
    }
    __syncthreads();
  }
  // epilogue: (acc + bd[col]) * rsqrt(max(out_deg,1)) -> bf16
  const int fr = fq * 4;
#pragma unroll
  for (int mi = 0; mi < 2; ++mi) {
#pragma unroll
    for (int r = 0; r < 4; ++r) {
      int row = block_m + mrow + mi * 16 + fr + r;
      if (row < N_NODES) {
        float ns = rsqrtf(fmaxf((float)out_deg[row], 1.0f));
#pragma unroll
        for (int ni = 0; ni < 4; ++ni) {
          int col = ncol + ni * 16 + fm;
          float val = (acc[mi][ni][r] + bd[col]) * ns;
          hbf[(size_t)row * OUT_DIM + col] = f2bf(val);
        }
      }
    }
  }
}

// ---------------- aggregation: one wave per dst node ----------------
// 16/8/4/1-deep ILP ladder: Poisson(16) degrees -> typical node handled by
// ONE 16-wide group with 16 independent 256B gathers in flight (vs 4 before).
// No masked over-fetch: exact-width groups, scalar tail.

__global__ __launch_bounds__(256) void agg_kernel(
    const unsigned short* __restrict__ hbf, const int* __restrict__ row_start,
    const int* __restrict__ edge_src, unsigned short* __restrict__ aggb) {
  const int wave = threadIdx.x >> 6;
  const int lane = threadIdx.x & 63;
  const int v = blockIdx.x * 4 + wave;
  if (v >= N_NODES) return;
  const int beg = row_start[v];
  const int end = row_start[v + 1];
  const unsigned* hp = (const unsigned*)hbf;  // 64 uints per node row (128 bf16)
  float a0 = 0.f, a1 = 0.f;
  for (int c = beg; c < end; c += 64) {
    int rem = end - c;
    int n = rem < 64 ? rem : 64;
    int sv = (c + lane < end) ? edge_src[c + lane] : 0;
    int j = 0;
    for (; j + 16 <= n; j += 16) {
      unsigned u[16];
#pragma unroll
      for (int t = 0; t < 16; ++t) {
        int s = __shfl(sv, j + t);
        u[t] = hp[(size_t)s * 64 + lane];
      }
#pragma unroll
      for (int t = 0; t < 16; ++t) {
        a0 += bflo(u[t]);
        a1 += bfhi(u[t]);
      }
    }
    for (; j + 8 <= n; j += 8) {
      unsigned u[8];
#pragma unroll
      for (int t = 0; t < 8; ++t) {
        int s = __shfl(sv, j + t);
        u[t] = hp[(size_t)s * 64 + lane];
      }
#pragma unroll
      for (int t = 0; t < 8; ++t) {
        a0 += bflo(u[t]);
        a1 += bfhi(u[t]);
      }
    }
    for (; j + 4 <= n; j += 4) {
      unsigned u[4];
#pragma unroll
      for (int t = 0; t < 4; ++t) {
        int s = __shfl(sv, j + t);
        u[t] = hp[(size_t)s * 64 + lane];
      }
#pragma unroll
      for (int t = 0; t < 4; ++t) {
        a0 += bflo(u[t]);
        a1 += bfhi(u[t]);
      }
    }
    for (; j < n; ++j) {
      int s = __shfl(sv, j);
      unsigned u = hp[(size_t)s * 64 + lane];
      a0 += bflo(u);
      a1 += bfhi(u);
    }
  }
  float nd = rsqrtf(fmaxf((float)(end - beg), 1.0f));
  a0 *= nd; a1 *= nd;
  unsigned o = (unsigned)f2bf(a0) | ((unsigned)f2bf(a1) << 16);
  ((unsigned*)aggb)[(size_t)v * 64 + lane] = o;
}

// ---------------- fold Wg@Wu and bg@Wu+bu ----------------

__global__ void wgu_kernel(const float* __restrict__ Wg, const float* __restrict__ Wu,
                           unsigned short* __restrict__ WguT) {
  int i = blockIdx.x * 256 + threadIdx.x;     // over 128*768
  if (i >= 128 * 768) return;
  int r = i / 768, c = i % 768;
  float s = 0.f;
  for (int k = 0; k < 128; ++k) s += Wg[r * 128 + k] * Wu[(size_t)k * 768 + c];
  WguT[(size_t)c * 128 + r] = f2bf(s);        // stored transposed: [n=768][k=128]
}

__global__ void bgu_kernel(const float* __restrict__ bg, const float* __restrict__ Wu,
                           const float* __restrict__ bu, float* __restrict__ bgu) {
  int c = blockIdx.x * 256 + threadIdx.x;
  if (c >= 768) return;
  float s = bu[c];
  for (int k = 0; k < 128; ++k) s += bg[k] * Wu[(size_t)k * 768 + c];
  bgu[c] = s;
}

// ---------------- GEMM3: out = agg_bf16 @ Wgu + bgu (fp32 out) ----------------
// BM=128, BN=128, K=128. Both K-halves loaded to registers upfront (single
// HBM-latency exposure), two LDS compute phases. Grid dim3(6, 782).
// (round-4 measured form, kept unchanged this round)

__global__ __launch_bounds__(256) void gemm3_kernel(
    const unsigned short* __restrict__ aggb, const unsigned short* __restrict__ WguT,
    const float* __restrict__ bgu, float* __restrict__ out) {
  __shared__ unsigned short a_lds[128][72];   // [m][k-half], pad 64->72
  __shared__ unsigned short b_lds[128][72];   // [n][k-half]
  const int tid = threadIdx.x;
  const int wave = tid >> 6;
  const int lane = tid & 63;
  const int m_off = (wave >> 1) * 64;
  const int n_off = (wave & 1) * 64;
  const int block_n = blockIdx.x * 128;   // 0..5
  const int block_m = blockIdx.y * 128;   // 0..781
  const int fm = lane & 15;
  const int fq = lane >> 4;

  const int sr = tid >> 3;           // row = sr + p*32
  const int sch = (tid & 7) * 8;     // col (shorts)

  // load BOTH K-halves into registers upfront: all 16 loads in flight at once
  uint4 av0[4], bv0[4], av1[4], bv1[4];
#pragma unroll
  for (int p = 0; p < 4; ++p) {
    int rr = sr + p * 32;
    int gr = block_m + rr;
    const unsigned short* ap = aggb + (size_t)gr * 128 + sch;
    const unsigned short* bp = WguT + (size_t)(block_n + rr) * 128 + sch;
    bool ok = gr < N_NODES;
    av0[p] = ok ? *(const uint4*)(ap)      : make_uint4(0u, 0u, 0u, 0u);
    av1[p] = ok ? *(const uint4*)(ap + 64) : make_uint4(0u, 0u, 0u, 0u);
    bv0[p] = *(const uint4*)(bp);
    bv1[p] = *(const uint4*)(bp + 64);
  }

  f32x4 acc[4][4] = {};

  // ---- phase 0: k = 0..63 ----
#pragma unroll
  for (int p = 0; p < 4; ++p) {
    int rr = sr + p * 32;
    *(uint4*)&a_lds[rr][sch] = av0[p];
    *(uint4*)&b_lds[rr][sch] = bv0[p];
  }
  __syncthreads();
#pragma unroll
  for (int ks = 0; ks < 64; ks += 32) {
    bf16x8 af[4], bfr[4];
    int kc = ks + fq * 8;
#pragma unroll
    for (int i = 0; i < 4; ++i) af[i] = *(const bf16x8*)&a_lds[m_off + i * 16 + fm][kc];
#pragma unroll
    for (int i = 0; i < 4; ++i) bfr[i] = *(const bf16x8*)&b_lds[n_off + i * 16 + fm][kc];
#pragma unroll
    for (int mi = 0; mi < 4; ++mi)
#pragma unroll
      for (int ni = 0; ni < 4; ++ni)
        acc[mi][ni] = __builtin_amdgcn_mfma_f32_16x16x32_bf16(af[mi], bfr[ni], acc[mi][ni], 0, 0, 0);
  }
  __syncthreads();
  // ---- phase 1: k = 64..127 ----
#pragma unroll
  for (int p = 0; p < 4; ++p) {
    int rr = sr + p * 32;
    *(uint4*)&a_lds[rr][sch] = av1[p];
    *(uint4*)&b_lds[rr][sch] = bv1[p];
  }
  __syncthreads();
#pragma unroll
  for (int ks = 0; ks < 64; ks += 32) {
    bf16x8 af[4], bfr[4];
    int kc = ks + fq * 8;
#pragma unroll
    for (int i = 0; i < 4; ++i) af[i] = *(const bf16x8*)&a_lds[m_off + i * 16 + fm][kc];
#pragma unroll
    for (int i = 0; i < 4; ++i) bfr[i] = *(const bf16x8*)&b_lds[n_off + i * 16 + fm][kc];
#pragma unroll
    for (int mi = 0; mi < 4; ++mi)
#pragma unroll
      for (int ni = 0; ni < 4; ++ni)
        acc[mi][ni] = __builtin_amdgcn_mfma_f32_16x16x32_bf16(af[mi], bfr[ni], acc[mi][ni], 0, 0, 0);
  }

  const int fr = fq * 4;
#pragma unroll
  for (int mi = 0; mi < 4; ++mi) {
#pragma unroll
    for (int r = 0; r < 4; ++r) {
      int row = block_m + m_off + mi * 16 + fr + r;
      if (row < N_NODES) {
#pragma unroll
        for (int ni = 0; ni < 4; ++ni) {
          int col = block_n + n_off + ni * 16 + fm;
          out[(size_t)row * IN_DIM + col] = acc[mi][ni][r] + bgu[col];
        }
      }
    }
  }
}

// ---------------- launch ----------------

extern "C" void kernel_launch(void* const* d_in, const int* in_sizes, int n_in,
                              void* d_out, int out_size, void* d_ws, size_t ws_size,
                              hipStream_t stream) {
  (void)in_sizes; (void)n_in; (void)out_size; (void)ws_size;
  const float* feat = (const float*)d_in[0];
  const float* Wd   = (const float*)d_in[1];
  const float* bd   = (const float*)d_in[2];
  const float* Wg   = (const float*)d_in[3];
  const float* bg   = (const float*)d_in[4];
  const float* Wu   = (const float*)d_in[5];
  const float* bu   = (const float*)d_in[6];
  const int*   src  = (const int*)d_in[7];
  const int*   dst  = (const int*)d_in[8];
  float* out = (float*)d_out;

  char* ws = (char*)d_ws;
  unsigned short* hbf       = (unsigned short*)(ws + 0);          // 25,600,000
  unsigned short* aggb      = (unsigned short*)(ws + 25600000);   // 25,600,000
  int*            edge_srcs = (int*)(ws + 51200000);              //  6,400,000
  int*            out_deg   = (int*)(ws + 57600000);              //    400,000
  int*            in_deg    = (int*)(ws + 58000000);              //    400,000
  int*            row_start = (int*)(ws + 58400000);              //    400,004
  int*            cursor    = (int*)(ws + 58800128);              //    400,000
  unsigned short* WguT      = (unsigned short*)(ws + 59600128);   //    196,608
  float*          bgu       = (float*)(ws + 59796736);            //      3,072
  unsigned short* WdT       = (unsigned short*)(ws + 59799808);   //    196,608
  int*            blk_sums  = (int*)(ws + 59996416);              //        512
  int*            blk_off   = (int*)(ws + 59996928);              //        512

  // zero both degree arrays (contiguous 800,000 B)
  hipMemsetAsync(out_deg, 0, 800000, stream);
  deg_kernel<<<(N_EDGES + 255) / 256, 256, 0, stream>>>(src, dst, out_deg, in_deg);
  scanA_kernel<<<(N_NODES + 1023) / 1024, 256, 0, stream>>>(in_deg, row_start, blk_sums);
  scanB_kernel<<<1, 128, 0, stream>>>(blk_sums, blk_off);
  scanC_kernel<<<(N_NODES + 255) / 256, 256, 0, stream>>>(row_start, blk_off, cursor);
  scatter_kernel<<<(N_EDGES + 255) / 256, 256, 0, stream>>>(src, dst, cursor, edge_srcs);
  wdt_kernel<<<128, 768, 0, stream>>>(Wd, WdT);
  gemm1_kernel<<<(N_NODES + 63) / 64, 256, 0, stream>>>(feat, WdT, bd, out_deg, hbf);
  agg_kernel<<<(N_NODES + 3) / 4, 256, 0, stream>>>(hbf, row_start, edge_srcs, aggb);
  wgu_kernel<<<(128 * 768 + 255) / 256, 256, 0, stream>>>(Wg, Wu, WguT);
  bgu_kernel<<<3, 256, 0, stream>>>(bg, Wu, bu, bgu);
  gemm3_kernel<<<dim3(6, (N_NODES + 127) / 128), 256, 0, stream>>>(aggb, WguT, bgu, out);
}